// Round 1
// baseline (1405.052 us; speedup 1.0000x reference)
//
#include <hip/hip_runtime.h>
#include <hip/hip_bf16.h>
#include <cstdint>

// ---------------------------------------------------------------------------
// GraphSAGE inference, fp32 baseline.
// Pipeline per launch (all on `stream`, graph-capture safe):
//   1. memset deg/cursor
//   2. count_deg:    deg[dst[e]]++                        (int atomics)
//   3. scan_kernel:  row_start = exclusive_scan(deg)      (1 block)
//   4. scatter_edges: csr[row_start[d] + cursor[d]++] = src[e]
//   5. agg256(x)          -> A1
//   6. gemm(x, A1, W0)    -> H0   (relu)
//   7. agg256(H0)         -> A1
//   8. gemm(H0, A1, W1)   -> h1 (= d_out + N*64)  (relu)
//   9. gemm(h1 @ Wn2)     -> H0 (N x 64)      [agg commutes with matmul]
//  10. agg64(H0)          -> A1
//  11. gemm(h1 @ Ws2) + A1 + b2 -> h2 (= d_out)
// ---------------------------------------------------------------------------

#define GEMM_BM 128
#define GEMM_BN 64
#define GEMM_BK 16

__global__ void count_deg_kernel(const int* __restrict__ dst, int* __restrict__ deg, int E) {
    int i = blockIdx.x * blockDim.x + threadIdx.x;
    if (i < E) atomicAdd(&deg[dst[i]], 1);
}

// Single-block exclusive scan: row_start[0]=0, row_start[i+1]=sum(deg[0..i]).
__global__ void scan_kernel(const int* __restrict__ deg, int* __restrict__ row_start, int n) {
    __shared__ int sdata[1024];
    __shared__ int carry;
    const int t = threadIdx.x;
    if (t == 0) { carry = 0; row_start[0] = 0; }
    __syncthreads();
    for (int base = 0; base < n; base += 1024) {
        int i = base + t;
        int v = (i < n) ? deg[i] : 0;
        sdata[t] = v;
        __syncthreads();
        for (int off = 1; off < 1024; off <<= 1) {
            int x = (t >= off) ? sdata[t - off] : 0;
            __syncthreads();
            sdata[t] += x;
            __syncthreads();
        }
        if (i < n) row_start[i + 1] = carry + sdata[t];
        __syncthreads();
        if (t == 0) carry += sdata[1023];
        __syncthreads();
    }
}

__global__ void scatter_edges_kernel(const int* __restrict__ src, const int* __restrict__ dst,
                                     const int* __restrict__ row_start, int* __restrict__ cursor,
                                     int* __restrict__ csr, int E) {
    int i = blockIdx.x * blockDim.x + threadIdx.x;
    if (i < E) {
        int d = dst[i];
        int pos = atomicAdd(&cursor[d], 1);
        csr[row_start[d] + pos] = src[i];
    }
}

// One wave per node; lane handles a float4 slice of the 256-wide row.
__global__ __launch_bounds__(256) void agg_kernel256(
    const float* __restrict__ h, const int* __restrict__ row_start,
    const int* __restrict__ csr, float* __restrict__ out, int n) {
    int wv = (blockIdx.x * blockDim.x + threadIdx.x) >> 6;
    int lane = threadIdx.x & 63;
    if (wv >= n) return;
    int s0 = row_start[wv], s1 = row_start[wv + 1];
    float4 acc = make_float4(0.f, 0.f, 0.f, 0.f);
    for (int e = s0; e < s1; ++e) {
        int s = csr[e];
        const float4 v = *reinterpret_cast<const float4*>(h + (size_t)s * 256 + lane * 4);
        acc.x += v.x; acc.y += v.y; acc.z += v.z; acc.w += v.w;
    }
    float sc = 1.0f / (float)max(s1 - s0, 1);
    float4 o = make_float4(acc.x * sc, acc.y * sc, acc.z * sc, acc.w * sc);
    *reinterpret_cast<float4*>(out + (size_t)wv * 256 + lane * 4) = o;
}

// One wave per node; lane handles one float of the 64-wide row.
__global__ __launch_bounds__(256) void agg_kernel64(
    const float* __restrict__ t, const int* __restrict__ row_start,
    const int* __restrict__ csr, float* __restrict__ out, int n) {
    int wv = (blockIdx.x * blockDim.x + threadIdx.x) >> 6;
    int lane = threadIdx.x & 63;
    if (wv >= n) return;
    int s0 = row_start[wv], s1 = row_start[wv + 1];
    float acc = 0.f;
    for (int e = s0; e < s1; ++e) {
        int s = csr[e];
        acc += t[(size_t)s * 64 + lane];
    }
    float sc = 1.0f / (float)max(s1 - s0, 1);
    out[(size_t)wv * 64 + lane] = acc * sc;
}

// C[M,N] = act( A@Ws (+ G@Wn) (+ bias) (+ extra) ), all row-major fp32, K mult of 16.
// 256 threads, 128x64 tile, each thread 8x4 outputs.
__global__ __launch_bounds__(256) void gemm_fused(
    const float* __restrict__ A, const float* __restrict__ G,
    const float* __restrict__ Ws, const float* __restrict__ Wn,
    const float* __restrict__ bias, const float* __restrict__ extra,
    float* __restrict__ C, int M, int N, int K, int doRelu) {
    __shared__ float As[GEMM_BK][GEMM_BM + 4];
    __shared__ float Bs[GEMM_BK][GEMM_BN + 4];
    const int tid = threadIdx.x;
    const int tx = tid & 15;   // n-group (4 cols each)
    const int ty = tid >> 4;   // m-group (8 rows each)
    const int row0 = blockIdx.x * GEMM_BM;
    const int col0 = blockIdx.y * GEMM_BN;

    float acc[8][4];
#pragma unroll
    for (int i = 0; i < 8; i++)
#pragma unroll
        for (int j = 0; j < 4; j++) acc[i][j] = 0.f;

    const int npass = (G != nullptr) ? 2 : 1;
    for (int pass = 0; pass < npass; ++pass) {
        const float* __restrict__ Ap = pass ? G : A;
        const float* __restrict__ Wp = pass ? Wn : Ws;
        for (int k0 = 0; k0 < K; k0 += GEMM_BK) {
            // A tile 128x16 = 512 float4 loads, 2 per thread; store transposed As[k][m]
#pragma unroll
            for (int h = 0; h < 2; ++h) {
                int id = tid + h * 256;
                int r = id >> 2;       // 0..127
                int cg = id & 3;       // k-group of 4
                int gr = row0 + r;
                float4 v = make_float4(0.f, 0.f, 0.f, 0.f);
                if (gr < M)
                    v = *reinterpret_cast<const float4*>(Ap + (size_t)gr * K + k0 + cg * 4);
                As[cg * 4 + 0][r] = v.x;
                As[cg * 4 + 1][r] = v.y;
                As[cg * 4 + 2][r] = v.z;
                As[cg * 4 + 3][r] = v.w;
            }
            // B tile 16x64 = 256 float4 loads, 1 per thread
            {
                int kr = tid >> 4;   // 0..15
                int ng = tid & 15;   // 0..15
                float4 v = *reinterpret_cast<const float4*>(
                    Wp + (size_t)(k0 + kr) * N + col0 + ng * 4);
                *reinterpret_cast<float4*>(&Bs[kr][ng * 4]) = v;
            }
            __syncthreads();
#pragma unroll
            for (int k = 0; k < GEMM_BK; k++) {
                float a[8], b[4];
#pragma unroll
                for (int i = 0; i < 8; i++) a[i] = As[k][ty * 8 + i];
#pragma unroll
                for (int j = 0; j < 4; j++) b[j] = Bs[k][tx * 4 + j];
#pragma unroll
                for (int i = 0; i < 8; i++)
#pragma unroll
                    for (int j = 0; j < 4; j++) acc[i][j] = fmaf(a[i], b[j], acc[i][j]);
            }
            __syncthreads();
        }
    }
#pragma unroll
    for (int i = 0; i < 8; i++) {
        int r = row0 + ty * 8 + i;
        if (r >= M) continue;
#pragma unroll
        for (int j = 0; j < 4; j++) {
            int c = col0 + tx * 4 + j;
            float v = acc[i][j];
            if (bias) v += bias[c];
            if (extra) v += extra[(size_t)r * N + c];
            if (doRelu) v = fmaxf(v, 0.f);
            C[(size_t)r * N + c] = v;
        }
    }
}

extern "C" void kernel_launch(void* const* d_in, const int* in_sizes, int n_in,
                              void* d_out, int out_size, void* d_ws, size_t ws_size,
                              hipStream_t stream) {
    const float* x   = (const float*)d_in[0];
    const int*   src = (const int*)d_in[1];
    const int*   dst = (const int*)d_in[2];
    const float* Ws0 = (const float*)d_in[3];
    const float* Wn0 = (const float*)d_in[4];
    const float* b0  = (const float*)d_in[5];
    const float* Ws1 = (const float*)d_in[6];
    const float* Wn1 = (const float*)d_in[7];
    const float* b1  = (const float*)d_in[8];
    const float* Ws2 = (const float*)d_in[9];
    const float* Wn2 = (const float*)d_in[10];
    const float* b2  = (const float*)d_in[11];

    const int N = in_sizes[0] / 256;   // 50000 nodes
    const int E = in_sizes[1];         // 1600000 edges

    float* out = (float*)d_out;
    float* h2 = out;                        // N x 64  (output 0)
    float* h1 = out + (size_t)N * 64;       // N x 256 (output 1)

    // workspace layout
    char* w = (char*)d_ws;
    int* deg       = (int*)w;  w += (size_t)N * 4;
    int* cursor    = (int*)w;  w += (size_t)N * 4;
    int* row_start = (int*)w;  w += (size_t)(N + 1) * 4;
    int* csr       = (int*)w;  w += (size_t)E * 4;
    w = (char*)(((uintptr_t)w + 15) & ~(uintptr_t)15);
    float* A1 = (float*)w;     w += (size_t)N * 256 * 4;   // aggregation buffer
    float* H0 = (float*)w;     w += (size_t)N * 256 * 4;   // hidden buffer

    // 1. zero deg + cursor (contiguous)
    hipMemsetAsync(deg, 0, (size_t)N * 2 * 4, stream);

    // 2-4. build CSR by dst
    count_deg_kernel<<<(E + 255) / 256, 256, 0, stream>>>(dst, deg, E);
    scan_kernel<<<1, 1024, 0, stream>>>(deg, row_start, N);
    scatter_edges_kernel<<<(E + 255) / 256, 256, 0, stream>>>(src, dst, row_start, cursor, csr, E);

    dim3 aggGrid((N + 3) / 4);   // 4 waves per 256-thread block, 1 node per wave
    dim3 gemmBig((N + GEMM_BM - 1) / GEMM_BM, 256 / GEMM_BN);
    dim3 gemmSmall((N + GEMM_BM - 1) / GEMM_BM, 1);

    // 5-6. layer 0
    agg_kernel256<<<aggGrid, 256, 0, stream>>>(x, row_start, csr, A1, N);
    gemm_fused<<<gemmBig, 256, 0, stream>>>(x, A1, Ws0, Wn0, b0, nullptr, H0, N, 256, 256, 1);

    // 7-8. layer 1 (h1 written straight into d_out)
    agg_kernel256<<<aggGrid, 256, 0, stream>>>(H0, row_start, csr, A1, N);
    gemm_fused<<<gemmBig, 256, 0, stream>>>(H0, A1, Ws1, Wn1, b1, nullptr, h1, N, 256, 256, 1);

    // 9-11. layer 2: agg(h1)@Wn2 == agg(h1@Wn2)  -> aggregate in 64-dim space
    gemm_fused<<<gemmSmall, 256, 0, stream>>>(h1, nullptr, Wn2, nullptr, nullptr, nullptr,
                                              H0, N, 64, 256, 0);
    agg_kernel64<<<aggGrid, 256, 0, stream>>>(H0, row_start, csr, A1, N);
    gemm_fused<<<gemmSmall, 256, 0, stream>>>(h1, nullptr, Ws2, nullptr, b2, A1,
                                              h2, N, 64, 256, 0);
}

// Round 2
// 1068.204 us; speedup vs baseline: 1.3153x; 1.3153x over previous
//
#include <hip/hip_runtime.h>
#include <hip/hip_bf16.h>
#include <cstdint>

// ---------------------------------------------------------------------------
// GraphSAGE inference, bf16 data plane + MFMA GEMMs.
//   CSR build (int atomics + 1-block scan)  [fp32-exact]
//   x -> bf16; weights -> bf16 transposed [n][k]
//   agg256(xb) -> A1b;  MFMA gemm([xb|A1b] @ Wt0) +b0 relu -> H0b
//   agg256(H0b) -> A1b; MFMA gemm([H0b|A1b] @ Wt1) +b1 relu -> h1(fp32) + h1b
//   MFMA gemm(h1b @ Wn2t) -> Tb;  agg64(Tb) -> A64(fp32)
//   MFMA gemm(h1b @ Ws2t) + A64 + b2 -> h2(fp32)
// All accumulation fp32. Layer-2 uses agg(h@W) == agg(h)@W to aggregate 64-wide.
// ---------------------------------------------------------------------------

typedef __attribute__((ext_vector_type(8))) short  frag_ab;  // 8 bf16
typedef __attribute__((ext_vector_type(4))) float  f32x4;

__device__ __forceinline__ unsigned short f2b(float f) {
    __hip_bfloat16 h = __float2bfloat16(f);
    return *reinterpret_cast<unsigned short*>(&h);
}
__device__ __forceinline__ float b2f(unsigned int u) {
    return __uint_as_float(u << 16);
}

// ---------------- CSR build ----------------
__global__ void count_deg_kernel(const int* __restrict__ dst, int* __restrict__ deg, int E) {
    int i = blockIdx.x * blockDim.x + threadIdx.x;
    if (i < E) atomicAdd(&deg[dst[i]], 1);
}

__global__ void scan_kernel(const int* __restrict__ deg, int* __restrict__ row_start, int n) {
    __shared__ int sdata[1024];
    __shared__ int carry;
    const int t = threadIdx.x;
    if (t == 0) { carry = 0; row_start[0] = 0; }
    __syncthreads();
    for (int base = 0; base < n; base += 1024) {
        int i = base + t;
        int v = (i < n) ? deg[i] : 0;
        sdata[t] = v;
        __syncthreads();
        for (int off = 1; off < 1024; off <<= 1) {
            int x = (t >= off) ? sdata[t - off] : 0;
            __syncthreads();
            sdata[t] += x;
            __syncthreads();
        }
        if (i < n) row_start[i + 1] = carry + sdata[t];
        __syncthreads();
        if (t == 0) carry += sdata[1023];
        __syncthreads();
    }
}

__global__ void scatter_edges_kernel(const int* __restrict__ src, const int* __restrict__ dst,
                                     const int* __restrict__ row_start, int* __restrict__ cursor,
                                     int* __restrict__ csr, int E) {
    int i = blockIdx.x * blockDim.x + threadIdx.x;
    if (i < E) {
        int d = dst[i];
        int pos = atomicAdd(&cursor[d], 1);
        csr[row_start[d] + pos] = src[i];
    }
}

// ---------------- conversions ----------------
__global__ void f32_to_bf16_kernel(const float* __restrict__ in,
                                   unsigned short* __restrict__ out, int n4) {
    int i = blockIdx.x * blockDim.x + threadIdx.x;
    if (i >= n4) return;
    float4 v = *reinterpret_cast<const float4*>(in + (size_t)i * 4);
    ushort4 o = { f2b(v.x), f2b(v.y), f2b(v.z), f2b(v.w) };
    *reinterpret_cast<ushort4*>(out + (size_t)i * 4) = o;
}

// Wt[n*Ktot + koff + k] = bf16(W[k*N + n]); idx = k*N + n for coalesced reads.
__global__ void wt_transpose_kernel(const float* __restrict__ W, unsigned short* __restrict__ Wt,
                                    int K, int N, int koff, int Ktot) {
    int idx = blockIdx.x * blockDim.x + threadIdx.x;
    if (idx >= K * N) return;
    int k = idx / N, n = idx - k * N;
    Wt[(size_t)n * Ktot + koff + k] = f2b(W[idx]);
}

// ---------------- aggregation (gather-mean via CSR) ----------------
// one wave per node; lane covers 4 bf16 of the 256-wide row (8 B)
__global__ __launch_bounds__(256) void agg256_bf16(
    const unsigned short* __restrict__ h, const int* __restrict__ row_start,
    const int* __restrict__ csr, unsigned short* __restrict__ out, int n) {
    int wv = (blockIdx.x * blockDim.x + threadIdx.x) >> 6;
    int lane = threadIdx.x & 63;
    if (wv >= n) return;
    int s0 = row_start[wv], s1 = row_start[wv + 1];
    float a0 = 0.f, a1 = 0.f, a2 = 0.f, a3 = 0.f;
    for (int e = s0; e < s1; ++e) {
        int s = csr[e];
        uint2 v = *reinterpret_cast<const uint2*>(h + (size_t)s * 256 + lane * 4);
        a0 += b2f(v.x & 0xffffu); a1 += b2f(v.x >> 16);
        a2 += b2f(v.y & 0xffffu); a3 += b2f(v.y >> 16);
    }
    float sc = 1.0f / (float)max(s1 - s0, 1);
    ushort4 o = { f2b(a0 * sc), f2b(a1 * sc), f2b(a2 * sc), f2b(a3 * sc) };
    *reinterpret_cast<ushort4*>(out + (size_t)wv * 256 + lane * 4) = o;
}

// one wave per node; lane covers 1 bf16 of the 64-wide row; fp32 out
__global__ __launch_bounds__(256) void agg64_bf16(
    const unsigned short* __restrict__ t, const int* __restrict__ row_start,
    const int* __restrict__ csr, float* __restrict__ out, int n) {
    int wv = (blockIdx.x * blockDim.x + threadIdx.x) >> 6;
    int lane = threadIdx.x & 63;
    if (wv >= n) return;
    int s0 = row_start[wv], s1 = row_start[wv + 1];
    float acc = 0.f;
    for (int e = s0; e < s1; ++e) {
        int s = csr[e];
        acc += b2f((unsigned int)t[(size_t)s * 64 + lane]);
    }
    float sc = 1.0f / (float)max(s1 - s0, 1);
    out[(size_t)wv * 64 + lane] = acc * sc;
}

// ---------------- MFMA GEMM ----------------
// C[M,Ntot] = act( [A|G] @ Wt^T + bias + extra ), A/G bf16 [M][256] row-major,
// Wt bf16 [Ntot][Ktot] (pre-transposed), acc fp32.
// Tile 128x64, BK=32, 256 threads = 4 waves in 2(m)x2(n); per wave 4x2 mfma tiles.
#define TM 128
#define TN 64
#define TK 32

__global__ __launch_bounds__(256) void gemm_mfma(
    const unsigned short* __restrict__ A, const unsigned short* __restrict__ G,
    const unsigned short* __restrict__ Wt,
    const float* __restrict__ bias, const float* __restrict__ extra,
    float* __restrict__ outF, unsigned short* __restrict__ outB,
    int M, int Ntot, int Ktot, int relu) {
    __shared__ unsigned short Asb[TM][TK + 8];   // 128 x 40
    __shared__ unsigned short Bsb[TN][TK + 8];   // 64 x 40

    const int tid = threadIdx.x;
    const int row0 = blockIdx.x * TM;
    const int col0 = blockIdx.y * TN;

    const int w = tid >> 6, lane = tid & 63;
    const int mw = (w & 1) * 64;     // wave m-offset
    const int nw = (w >> 1) * 32;    // wave n-offset
    const int lm = lane & 15, lq = lane >> 4;

    f32x4 acc[4][2];
#pragma unroll
    for (int i = 0; i < 4; i++)
#pragma unroll
        for (int j = 0; j < 2; j++) acc[i][j] = (f32x4)(0.f);

    for (int k0 = 0; k0 < Ktot; k0 += TK) {
        const unsigned short* __restrict__ Ap = (G != nullptr && k0 >= 256) ? G : A;
        const int kl = k0 & 255;
        // stage A tile: 128 rows x 32 k, 2 x 16B per thread
#pragma unroll
        for (int h = 0; h < 2; ++h) {
            int id = tid + h * 256;
            int r = id >> 2;
            int kg = (id & 3) * 8;
            int gr = row0 + r;
            uint4 v = make_uint4(0u, 0u, 0u, 0u);
            if (gr < M)
                v = *reinterpret_cast<const uint4*>(Ap + (size_t)gr * 256 + kl + kg);
            *reinterpret_cast<uint4*>(&Asb[r][kg]) = v;
        }
        // stage B tile: 64 n-rows x 32 k, 1 x 16B per thread
        {
            int n = tid >> 2;
            int kg = (tid & 3) * 8;
            uint4 v = *reinterpret_cast<const uint4*>(Wt + (size_t)(col0 + n) * Ktot + k0 + kg);
            *reinterpret_cast<uint4*>(&Bsb[n][kg]) = v;
        }
        __syncthreads();

        frag_ab a[4], b[2];
#pragma unroll
        for (int i = 0; i < 4; i++)
            a[i] = *reinterpret_cast<const frag_ab*>(&Asb[mw + i * 16 + lm][lq * 8]);
#pragma unroll
        for (int j = 0; j < 2; j++)
            b[j] = *reinterpret_cast<const frag_ab*>(&Bsb[nw + j * 16 + lm][lq * 8]);
#pragma unroll
        for (int i = 0; i < 4; i++)
#pragma unroll
            for (int j = 0; j < 2; j++)
                acc[i][j] = __builtin_amdgcn_mfma_f32_16x16x32_bf16(a[i], b[j], acc[i][j], 0, 0, 0);
        __syncthreads();
    }

    // epilogue: C/D layout col=lane&15, row=lq*4+reg
#pragma unroll
    for (int i = 0; i < 4; i++) {
#pragma unroll
        for (int j = 0; j < 2; j++) {
            int cg = col0 + nw + j * 16 + lm;
#pragma unroll
            for (int r = 0; r < 4; r++) {
                int rg = row0 + mw + i * 16 + lq * 4 + r;
                if (rg >= M) continue;
                float v = acc[i][j][r];
                if (bias)  v += bias[cg];
                if (extra) v += extra[(size_t)rg * Ntot + cg];
                if (relu)  v = fmaxf(v, 0.f);
                if (outF) outF[(size_t)rg * Ntot + cg] = v;
                if (outB) outB[(size_t)rg * Ntot + cg] = f2b(v);
            }
        }
    }
}

// ---------------------------------------------------------------------------
extern "C" void kernel_launch(void* const* d_in, const int* in_sizes, int n_in,
                              void* d_out, int out_size, void* d_ws, size_t ws_size,
                              hipStream_t stream) {
    const float* x   = (const float*)d_in[0];
    const int*   src = (const int*)d_in[1];
    const int*   dst = (const int*)d_in[2];
    const float* Ws0 = (const float*)d_in[3];
    const float* Wn0 = (const float*)d_in[4];
    const float* b0  = (const float*)d_in[5];
    const float* Ws1 = (const float*)d_in[6];
    const float* Wn1 = (const float*)d_in[7];
    const float* b1  = (const float*)d_in[8];
    const float* Ws2 = (const float*)d_in[9];
    const float* Wn2 = (const float*)d_in[10];
    const float* b2  = (const float*)d_in[11];

    const int N = in_sizes[0] / 256;   // 50000
    const int E = in_sizes[1];         // 1600000

    float* out = (float*)d_out;
    float* h2 = out;                       // N x 64  (output 0)
    float* h1 = out + (size_t)N * 64;      // N x 256 (output 1, fp32)

    // ---- workspace layout (≈110 MB) ----
    char* w = (char*)d_ws;
    auto align16 = [](char* p) { return (char*)(((uintptr_t)p + 15) & ~(uintptr_t)15); };
    int* deg       = (int*)w;  w += (size_t)N * 4;
    int* cursor    = (int*)w;  w += (size_t)N * 4;
    int* row_start = (int*)w;  w += (size_t)(N + 1) * 4;
    int* csr       = (int*)w;  w += (size_t)E * 4;
    w = align16(w);
    unsigned short* Wt0   = (unsigned short*)w; w += (size_t)256 * 512 * 2;
    unsigned short* Wt1   = (unsigned short*)w; w += (size_t)256 * 512 * 2;
    unsigned short* Ws2t  = (unsigned short*)w; w += (size_t)64 * 256 * 2;
    unsigned short* Wn2t  = (unsigned short*)w; w += (size_t)64 * 256 * 2;
    w = align16(w);
    unsigned short* xb    = (unsigned short*)w; w += (size_t)N * 256 * 2;  // reused below
    unsigned short* A1b   = (unsigned short*)w; w += (size_t)N * 256 * 2;
    unsigned short* H0b   = (unsigned short*)w; w += (size_t)N * 256 * 2;
    unsigned short* h1b   = (unsigned short*)w; w += (size_t)N * 256 * 2;
    // xb region is dead after layer-0 GEMM; reuse it for layer-2 temporaries
    unsigned short* Tb  = xb;                                   // N x 64 bf16
    float*          A64 = (float*)align16((char*)(Tb + (size_t)N * 64)); // N x 64 fp32

    // ---- CSR build ----
    hipMemsetAsync(deg, 0, (size_t)N * 2 * 4, stream);
    count_deg_kernel<<<(E + 255) / 256, 256, 0, stream>>>(dst, deg, E);
    scan_kernel<<<1, 1024, 0, stream>>>(deg, row_start, N);
    scatter_edges_kernel<<<(E + 255) / 256, 256, 0, stream>>>(src, dst, row_start, cursor, csr, E);

    // ---- conversions ----
    {
        int n4 = N * 256 / 4;
        f32_to_bf16_kernel<<<(n4 + 255) / 256, 256, 0, stream>>>(x, xb, n4);
    }
    {
        int nt = 256 * 256;  // per 256x256 weight
        wt_transpose_kernel<<<(nt + 255) / 256, 256, 0, stream>>>(Ws0, Wt0, 256, 256, 0,   512);
        wt_transpose_kernel<<<(nt + 255) / 256, 256, 0, stream>>>(Wn0, Wt0, 256, 256, 256, 512);
        wt_transpose_kernel<<<(nt + 255) / 256, 256, 0, stream>>>(Ws1, Wt1, 256, 256, 0,   512);
        wt_transpose_kernel<<<(nt + 255) / 256, 256, 0, stream>>>(Wn1, Wt1, 256, 256, 256, 512);
        int nt2 = 256 * 64;
        wt_transpose_kernel<<<(nt2 + 255) / 256, 256, 0, stream>>>(Ws2, Ws2t, 256, 64, 0, 256);
        wt_transpose_kernel<<<(nt2 + 255) / 256, 256, 0, stream>>>(Wn2, Wn2t, 256, 64, 0, 256);
    }

    dim3 aggGrid((N + 3) / 4);                 // 4 waves/block, 1 node/wave
    dim3 gBig((N + TM - 1) / TM, 256 / TN);    // 391 x 4
    dim3 gSmall((N + TM - 1) / TM, 1);         // 391 x 1

    // ---- layer 0 ----
    agg256_bf16<<<aggGrid, 256, 0, stream>>>(xb, row_start, csr, A1b, N);
    gemm_mfma<<<gBig, 256, 0, stream>>>(xb, A1b, Wt0, b0, nullptr, nullptr, H0b,
                                        N, 256, 512, 1);
    // ---- layer 1 ----
    agg256_bf16<<<aggGrid, 256, 0, stream>>>(H0b, row_start, csr, A1b, N);
    gemm_mfma<<<gBig, 256, 0, stream>>>(H0b, A1b, Wt1, b1, nullptr, h1, h1b,
                                        N, 256, 512, 1);
    // ---- layer 2 (agg commutes with matmul; aggregate 64-wide) ----
    gemm_mfma<<<gSmall, 256, 0, stream>>>(h1b, nullptr, Wn2t, nullptr, nullptr, nullptr, Tb,
                                          N, 64, 256, 0);
    agg64_bf16<<<aggGrid, 256, 0, stream>>>(Tb, row_start, csr, A64, N);
    gemm_mfma<<<gSmall, 256, 0, stream>>>(h1b, nullptr, Ws2t, b2, A64, h2, nullptr,
                                          N, 64, 256, 0);
}

// Round 3
// 811.189 us; speedup vs baseline: 1.7321x; 1.3168x over previous
//
#include <hip/hip_runtime.h>
#include <hip/hip_bf16.h>
#include <cstdint>

// ---------------------------------------------------------------------------
// GraphSAGE inference, bf16 data plane + MFMA GEMMs.
//   CSR build (int atomics + 3-phase parallel scan)
//   x -> bf16; weights -> bf16 transposed [n][k]
//   agg256(xb) -> A1b;  MFMA gemm([xb|A1b] @ Wt0) +b0 relu -> H0b
//   agg256(H0b) -> A1b; MFMA gemm([H0b|A1b] @ Wt1) +b1 relu -> h1(fp32) + h1b
//   MFMA gemm(h1b @ Wn2t) -> Tb;  agg64(Tb) -> A64(fp32)
//   MFMA gemm(h1b @ Ws2t) + A64 + b2 -> h2(fp32)
// Aggregations: multi-edge-in-flight gathers (latency-bound fix, round 3).
// ---------------------------------------------------------------------------

typedef __attribute__((ext_vector_type(8))) short  frag_ab;  // 8 bf16
typedef __attribute__((ext_vector_type(4))) float  f32x4;

__device__ __forceinline__ unsigned short f2b(float f) {
    __hip_bfloat16 h = __float2bfloat16(f);
    return *reinterpret_cast<unsigned short*>(&h);
}
__device__ __forceinline__ float b2f(unsigned int u) {
    return __uint_as_float(u << 16);
}
// accumulate 8 bf16 (as uint4) into 8 fp32
__device__ __forceinline__ void acc8(float* a, uint4 v) {
    a[0] += __uint_as_float(v.x << 16);
    a[1] += __uint_as_float(v.x & 0xffff0000u);
    a[2] += __uint_as_float(v.y << 16);
    a[3] += __uint_as_float(v.y & 0xffff0000u);
    a[4] += __uint_as_float(v.z << 16);
    a[5] += __uint_as_float(v.z & 0xffff0000u);
    a[6] += __uint_as_float(v.w << 16);
    a[7] += __uint_as_float(v.w & 0xffff0000u);
}

// ---------------- CSR build ----------------
__global__ void count_deg_kernel(const int* __restrict__ dst, int* __restrict__ deg, int E) {
    int i = blockIdx.x * blockDim.x + threadIdx.x;
    if (i < E) atomicAdd(&deg[dst[i]], 1);
}

// phase 1: per-block (1024 elems) sums
__global__ __launch_bounds__(256) void scan_partial_kernel(
    const int* __restrict__ deg, int* __restrict__ partials, int n) {
    const int t = threadIdx.x;
    const int i0 = blockIdx.x * 1024 + t * 4;
    int sum = 0;
#pragma unroll
    for (int j = 0; j < 4; j++) { int i = i0 + j; if (i < n) sum += deg[i]; }
#pragma unroll
    for (int off = 32; off; off >>= 1) sum += __shfl_down(sum, off);
    __shared__ int ws[4];
    int lane = t & 63, wid = t >> 6;
    if (lane == 0) ws[wid] = sum;
    __syncthreads();
    if (t == 0) partials[blockIdx.x] = ws[0] + ws[1] + ws[2] + ws[3];
}

// phase 2: exclusive scan of partials in place (single wave, chunked w/ carry)
__global__ void scan_partials_kernel(int* __restrict__ p, int nb) {
    const int lane = threadIdx.x;  // 64 threads
    int carry = 0;
    for (int base = 0; base < nb; base += 64) {
        int i = base + lane;
        int v = (i < nb) ? p[i] : 0;
        int orig = v;
#pragma unroll
        for (int off = 1; off < 64; off <<= 1) {
            int x = __shfl_up(v, off);
            if (lane >= off) v += x;
        }
        int ex = carry + v - orig;
        if (i < nb) p[i] = ex;
        carry += __shfl(v, 63);
    }
}

// phase 3: in-block scan + block offset -> row_start[1..n]
__global__ __launch_bounds__(256) void scan_final_kernel(
    const int* __restrict__ deg, const int* __restrict__ pscan,
    int* __restrict__ row_start, int n) {
    const int t = threadIdx.x;
    const int i0 = blockIdx.x * 1024 + t * 4;
    int v0 = (i0 + 0 < n) ? deg[i0 + 0] : 0;
    int v1 = (i0 + 1 < n) ? deg[i0 + 1] : 0;
    int v2 = (i0 + 2 < n) ? deg[i0 + 2] : 0;
    int v3 = (i0 + 3 < n) ? deg[i0 + 3] : 0;
    int tot = v0 + v1 + v2 + v3;
    int lane = t & 63, wid = t >> 6;
    int inc = tot;
#pragma unroll
    for (int off = 1; off < 64; off <<= 1) {
        int x = __shfl_up(inc, off);
        if (lane >= off) inc += x;
    }
    __shared__ int wsum[4];
    if (lane == 63) wsum[wid] = inc;
    __syncthreads();
    int wbase = 0;
    for (int w2 = 0; w2 < wid; w2++) wbase += wsum[w2];
    int r = wbase + inc - tot + pscan[blockIdx.x];
    r += v0; if (i0 + 0 < n) row_start[i0 + 1] = r;
    r += v1; if (i0 + 1 < n) row_start[i0 + 2] = r;
    r += v2; if (i0 + 2 < n) row_start[i0 + 3] = r;
    r += v3; if (i0 + 3 < n) row_start[i0 + 4] = r;
    if (blockIdx.x == 0 && t == 0) row_start[0] = 0;
}

__global__ void scatter_edges_kernel(const int* __restrict__ src, const int* __restrict__ dst,
                                     const int* __restrict__ row_start, int* __restrict__ cursor,
                                     int* __restrict__ csr, int E) {
    int i = blockIdx.x * blockDim.x + threadIdx.x;
    if (i < E) {
        int d = dst[i];
        int pos = atomicAdd(&cursor[d], 1);
        csr[row_start[d] + pos] = src[i];
    }
}

// ---------------- conversions ----------------
__global__ void f32_to_bf16_kernel(const float* __restrict__ in,
                                   unsigned short* __restrict__ out, int n4) {
    int i = blockIdx.x * blockDim.x + threadIdx.x;
    if (i >= n4) return;
    float4 v = *reinterpret_cast<const float4*>(in + (size_t)i * 4);
    ushort4 o = { f2b(v.x), f2b(v.y), f2b(v.z), f2b(v.w) };
    *reinterpret_cast<ushort4*>(out + (size_t)i * 4) = o;
}

__global__ void wt_transpose_kernel(const float* __restrict__ W, unsigned short* __restrict__ Wt,
                                    int K, int N, int koff, int Ktot) {
    int idx = blockIdx.x * blockDim.x + threadIdx.x;
    if (idx >= K * N) return;
    int k = idx / N, n = idx - k * N;
    Wt[(size_t)n * Ktot + koff + k] = f2b(W[idx]);
}

// ---------------- aggregation ----------------
// One wave per node. Half-wave h covers one edge's full 512B row (32 lanes x 16B).
// Main loop: 4 edges per half in flight (8 per wave). Cross-half combine via shfl.
__global__ __launch_bounds__(256) void agg256_bf16(
    const unsigned short* __restrict__ hsrc, const int* __restrict__ row_start,
    const int* __restrict__ csr, unsigned short* __restrict__ out, int n) {
    int wv = (blockIdx.x * blockDim.x + threadIdx.x) >> 6;
    int lane = threadIdx.x & 63;
    if (wv >= n) return;
    int s0 = row_start[wv], s1 = row_start[wv + 1];
    int deg = s1 - s0;
    const int half = lane >> 5;   // 0/1: which edge of the pair
    const int li   = lane & 31;   // 16B chunk -> columns li*8 .. li*8+7
    float a[8] = {0.f, 0.f, 0.f, 0.f, 0.f, 0.f, 0.f, 0.f};

    int e = s0;
    for (; e + 8 <= s1; e += 8) {
        int i0 = csr[e + half + 0];
        int i1 = csr[e + half + 2];
        int i2 = csr[e + half + 4];
        int i3 = csr[e + half + 6];
        uint4 v0 = *reinterpret_cast<const uint4*>(hsrc + (size_t)i0 * 256 + li * 8);
        uint4 v1 = *reinterpret_cast<const uint4*>(hsrc + (size_t)i1 * 256 + li * 8);
        uint4 v2 = *reinterpret_cast<const uint4*>(hsrc + (size_t)i2 * 256 + li * 8);
        uint4 v3 = *reinterpret_cast<const uint4*>(hsrc + (size_t)i3 * 256 + li * 8);
        acc8(a, v0); acc8(a, v1); acc8(a, v2); acc8(a, v3);
    }
    for (int t = e + half; t < s1; t += 2) {
        int i = csr[t];
        uint4 v = *reinterpret_cast<const uint4*>(hsrc + (size_t)i * 256 + li * 8);
        acc8(a, v);
    }
#pragma unroll
    for (int k = 0; k < 8; k++) a[k] += __shfl_xor(a[k], 32);
    if (half == 0) {
        float sc = 1.0f / (float)max(deg, 1);
        uint4 o;
        o.x = ((unsigned)f2b(a[1] * sc) << 16) | f2b(a[0] * sc);
        o.y = ((unsigned)f2b(a[3] * sc) << 16) | f2b(a[2] * sc);
        o.z = ((unsigned)f2b(a[5] * sc) << 16) | f2b(a[4] * sc);
        o.w = ((unsigned)f2b(a[7] * sc) << 16) | f2b(a[6] * sc);
        *reinterpret_cast<uint4*>(out + (size_t)wv * 256 + li * 8) = o;
    }
}

// One wave per node, 64-wide bf16 rows (128B). 8 lane-groups of 8; group g covers
// edge e+g, lane-in-group li covers 16B (8 cols). fp32 out.
__global__ __launch_bounds__(256) void agg64_bf16(
    const unsigned short* __restrict__ t, const int* __restrict__ row_start,
    const int* __restrict__ csr, float* __restrict__ out, int n) {
    int wv = (blockIdx.x * blockDim.x + threadIdx.x) >> 6;
    int lane = threadIdx.x & 63;
    if (wv >= n) return;
    int s0 = row_start[wv], s1 = row_start[wv + 1];
    int deg = s1 - s0;
    const int g  = lane >> 3;
    const int li = lane & 7;
    float a[8] = {0.f, 0.f, 0.f, 0.f, 0.f, 0.f, 0.f, 0.f};
    for (int e = s0 + g; e < s1; e += 8) {
        int i = csr[e];
        uint4 v = *reinterpret_cast<const uint4*>(t + (size_t)i * 64 + li * 8);
        acc8(a, v);
    }
#pragma unroll
    for (int k = 0; k < 8; k++) {
        a[k] += __shfl_xor(a[k], 8);
        a[k] += __shfl_xor(a[k], 16);
        a[k] += __shfl_xor(a[k], 32);
    }
    if (g == 0) {
        float sc = 1.0f / (float)max(deg, 1);
        float4 o0 = make_float4(a[0] * sc, a[1] * sc, a[2] * sc, a[3] * sc);
        float4 o1 = make_float4(a[4] * sc, a[5] * sc, a[6] * sc, a[7] * sc);
        *reinterpret_cast<float4*>(out + (size_t)wv * 64 + li * 8) = o0;
        *reinterpret_cast<float4*>(out + (size_t)wv * 64 + li * 8 + 4) = o1;
    }
}

// ---------------- MFMA GEMM (unchanged from round 2) ----------------
#define TM 128
#define TN 64
#define TK 32

__global__ __launch_bounds__(256) void gemm_mfma(
    const unsigned short* __restrict__ A, const unsigned short* __restrict__ G,
    const unsigned short* __restrict__ Wt,
    const float* __restrict__ bias, const float* __restrict__ extra,
    float* __restrict__ outF, unsigned short* __restrict__ outB,
    int M, int Ntot, int Ktot, int relu) {
    __shared__ unsigned short Asb[TM][TK + 8];
    __shared__ unsigned short Bsb[TN][TK + 8];

    const int tid = threadIdx.x;
    const int row0 = blockIdx.x * TM;
    const int col0 = blockIdx.y * TN;

    const int w = tid >> 6, lane = tid & 63;
    const int mw = (w & 1) * 64;
    const int nw = (w >> 1) * 32;
    const int lm = lane & 15, lq = lane >> 4;

    f32x4 acc[4][2];
#pragma unroll
    for (int i = 0; i < 4; i++)
#pragma unroll
        for (int j = 0; j < 2; j++) acc[i][j] = (f32x4)(0.f);

    for (int k0 = 0; k0 < Ktot; k0 += TK) {
        const unsigned short* __restrict__ Ap = (G != nullptr && k0 >= 256) ? G : A;
        const int kl = k0 & 255;
#pragma unroll
        for (int h = 0; h < 2; ++h) {
            int id = tid + h * 256;
            int r = id >> 2;
            int kg = (id & 3) * 8;
            int gr = row0 + r;
            uint4 v = make_uint4(0u, 0u, 0u, 0u);
            if (gr < M)
                v = *reinterpret_cast<const uint4*>(Ap + (size_t)gr * 256 + kl + kg);
            *reinterpret_cast<uint4*>(&Asb[r][kg]) = v;
        }
        {
            int nn = tid >> 2;
            int kg = (tid & 3) * 8;
            uint4 v = *reinterpret_cast<const uint4*>(Wt + (size_t)(col0 + nn) * Ktot + k0 + kg);
            *reinterpret_cast<uint4*>(&Bsb[nn][kg]) = v;
        }
        __syncthreads();

        frag_ab a[4], b[2];
#pragma unroll
        for (int i = 0; i < 4; i++)
            a[i] = *reinterpret_cast<const frag_ab*>(&Asb[mw + i * 16 + lm][lq * 8]);
#pragma unroll
        for (int j = 0; j < 2; j++)
            b[j] = *reinterpret_cast<const frag_ab*>(&Bsb[nw + j * 16 + lm][lq * 8]);
#pragma unroll
        for (int i = 0; i < 4; i++)
#pragma unroll
            for (int j = 0; j < 2; j++)
                acc[i][j] = __builtin_amdgcn_mfma_f32_16x16x32_bf16(a[i], b[j], acc[i][j], 0, 0, 0);
        __syncthreads();
    }

#pragma unroll
    for (int i = 0; i < 4; i++) {
#pragma unroll
        for (int j = 0; j < 2; j++) {
            int cg = col0 + nw + j * 16 + lm;
#pragma unroll
            for (int r = 0; r < 4; r++) {
                int rg = row0 + mw + i * 16 + lq * 4 + r;
                if (rg >= M) continue;
                float v = acc[i][j][r];
                if (bias)  v += bias[cg];
                if (extra) v += extra[(size_t)rg * Ntot + cg];
                if (relu)  v = fmaxf(v, 0.f);
                if (outF) outF[(size_t)rg * Ntot + cg] = v;
                if (outB) outB[(size_t)rg * Ntot + cg] = f2b(v);
            }
        }
    }
}

// ---------------------------------------------------------------------------
extern "C" void kernel_launch(void* const* d_in, const int* in_sizes, int n_in,
                              void* d_out, int out_size, void* d_ws, size_t ws_size,
                              hipStream_t stream) {
    const float* x   = (const float*)d_in[0];
    const int*   src = (const int*)d_in[1];
    const int*   dst = (const int*)d_in[2];
    const float* Ws0 = (const float*)d_in[3];
    const float* Wn0 = (const float*)d_in[4];
    const float* b0  = (const float*)d_in[5];
    const float* Ws1 = (const float*)d_in[6];
    const float* Wn1 = (const float*)d_in[7];
    const float* b1  = (const float*)d_in[8];
    const float* Ws2 = (const float*)d_in[9];
    const float* Wn2 = (const float*)d_in[10];
    const float* b2  = (const float*)d_in[11];

    const int N = in_sizes[0] / 256;   // 50000
    const int E = in_sizes[1];         // 1600000

    float* out = (float*)d_out;
    float* h2 = out;                       // N x 64  (output 0)
    float* h1 = out + (size_t)N * 64;      // N x 256 (output 1, fp32)

    // ---- workspace layout ----
    char* w = (char*)d_ws;
    auto align16 = [](char* p) { return (char*)(((uintptr_t)p + 15) & ~(uintptr_t)15); };
    int* deg       = (int*)w;  w += (size_t)N * 4;
    int* cursor    = (int*)w;  w += (size_t)N * 4;
    int* row_start = (int*)w;  w += (size_t)(N + 1) * 4;
    int* partials  = (int*)w;  w += 256 * 4;
    int* csr       = (int*)w;  w += (size_t)E * 4;
    w = align16(w);
    unsigned short* Wt0   = (unsigned short*)w; w += (size_t)256 * 512 * 2;
    unsigned short* Wt1   = (unsigned short*)w; w += (size_t)256 * 512 * 2;
    unsigned short* Ws2t  = (unsigned short*)w; w += (size_t)64 * 256 * 2;
    unsigned short* Wn2t  = (unsigned short*)w; w += (size_t)64 * 256 * 2;
    w = align16(w);
    unsigned short* xb    = (unsigned short*)w; w += (size_t)N * 256 * 2;
    unsigned short* A1b   = (unsigned short*)w; w += (size_t)N * 256 * 2;
    unsigned short* H0b   = (unsigned short*)w; w += (size_t)N * 256 * 2;
    unsigned short* h1b   = (unsigned short*)w; w += (size_t)N * 256 * 2;
    unsigned short* Tb  = xb;                                   // N x 64 bf16 (xb dead by then)
    float*          A64 = (float*)align16((char*)(Tb + (size_t)N * 64));

    const int nb = (N + 1023) / 1024;   // scan blocks

    // ---- CSR build ----
    hipMemsetAsync(deg, 0, (size_t)N * 2 * 4, stream);
    count_deg_kernel<<<(E + 255) / 256, 256, 0, stream>>>(dst, deg, E);
    scan_partial_kernel<<<nb, 256, 0, stream>>>(deg, partials, N);
    scan_partials_kernel<<<1, 64, 0, stream>>>(partials, nb);
    scan_final_kernel<<<nb, 256, 0, stream>>>(deg, partials, row_start, N);
    scatter_edges_kernel<<<(E + 255) / 256, 256, 0, stream>>>(src, dst, row_start, cursor, csr, E);

    // ---- conversions ----
    {
        int n4 = N * 256 / 4;
        f32_to_bf16_kernel<<<(n4 + 255) / 256, 256, 0, stream>>>(x, xb, n4);
    }
    {
        int nt = 256 * 256;
        wt_transpose_kernel<<<(nt + 255) / 256, 256, 0, stream>>>(Ws0, Wt0, 256, 256, 0,   512);
        wt_transpose_kernel<<<(nt + 255) / 256, 256, 0, stream>>>(Wn0, Wt0, 256, 256, 256, 512);
        wt_transpose_kernel<<<(nt + 255) / 256, 256, 0, stream>>>(Ws1, Wt1, 256, 256, 0,   512);
        wt_transpose_kernel<<<(nt + 255) / 256, 256, 0, stream>>>(Wn1, Wt1, 256, 256, 256, 512);
        int nt2 = 256 * 64;
        wt_transpose_kernel<<<(nt2 + 255) / 256, 256, 0, stream>>>(Ws2, Ws2t, 256, 64, 0, 256);
        wt_transpose_kernel<<<(nt2 + 255) / 256, 256, 0, stream>>>(Wn2, Wn2t, 256, 64, 0, 256);
    }

    dim3 aggGrid((N + 3) / 4);
    dim3 gBig((N + TM - 1) / TM, 256 / TN);
    dim3 gSmall((N + TM - 1) / TM, 1);

    // ---- layer 0 ----
    agg256_bf16<<<aggGrid, 256, 0, stream>>>(xb, row_start, csr, A1b, N);
    gemm_mfma<<<gBig, 256, 0, stream>>>(xb, A1b, Wt0, b0, nullptr, nullptr, H0b,
                                        N, 256, 512, 1);
    // ---- layer 1 ----
    agg256_bf16<<<aggGrid, 256, 0, stream>>>(H0b, row_start, csr, A1b, N);
    gemm_mfma<<<gBig, 256, 0, stream>>>(H0b, A1b, Wt1, b1, nullptr, h1, h1b,
                                        N, 256, 512, 1);
    // ---- layer 2 (agg commutes with matmul) ----
    gemm_mfma<<<gSmall, 256, 0, stream>>>(h1b, nullptr, Wn2t, nullptr, nullptr, nullptr, Tb,
                                          N, 64, 256, 0);
    agg64_bf16<<<aggGrid, 256, 0, stream>>>(Tb, row_start, csr, A64, N);
    gemm_mfma<<<gSmall, 256, 0, stream>>>(h1b, nullptr, Ws2t, b2, A64, h2, nullptr,
                                          N, 64, 256, 0);
}

// Round 4
// 753.451 us; speedup vs baseline: 1.8648x; 1.0766x over previous
//
#include <hip/hip_runtime.h>
#include <hip/hip_bf16.h>
#include <cstdint>

// ---------------------------------------------------------------------------
// GraphSAGE inference, bf16 data plane + MFMA GEMMs (async LDS staging).
//   CSR build (int atomics + 3-phase parallel scan)
//   agg256(xb) -> A1b;  gemm([xb|A1b] @ Wt0) +b0 relu -> H0b
//   agg256(H0b) -> A1b; gemm([H0b|A1b] @ Wt1) +b1 relu -> h1(fp32) + h1b
//   gemm(h1b @ [Ws2t;Wn2t]) -> Sself(fp32) , Tb(bf16)   [one pass over h1b]
//   agg64_final: h2 = Sself + mean_csr(Tb) + b2          [agg commutes w/ matmul]
// ---------------------------------------------------------------------------

typedef __attribute__((ext_vector_type(8))) short  frag_ab;  // 8 bf16
typedef __attribute__((ext_vector_type(4))) float  f32x4;

__device__ __forceinline__ unsigned short f2b(float f) {
    __hip_bfloat16 h = __float2bfloat16(f);
    return *reinterpret_cast<unsigned short*>(&h);
}
// accumulate 8 bf16 (as uint4) into 8 fp32
__device__ __forceinline__ void acc8(float* a, uint4 v) {
    a[0] += __uint_as_float(v.x << 16);
    a[1] += __uint_as_float(v.x & 0xffff0000u);
    a[2] += __uint_as_float(v.y << 16);
    a[3] += __uint_as_float(v.y & 0xffff0000u);
    a[4] += __uint_as_float(v.z << 16);
    a[5] += __uint_as_float(v.z & 0xffff0000u);
    a[6] += __uint_as_float(v.w << 16);
    a[7] += __uint_as_float(v.w & 0xffff0000u);
}

// async global->LDS, 16B per lane; lds base must be wave-uniform (HW adds lane*16)
__device__ __forceinline__ void gl_lds16(const void* g, void* l) {
    __builtin_amdgcn_global_load_lds(
        (const __attribute__((address_space(1))) unsigned int*)g,
        (__attribute__((address_space(3))) unsigned int*)l, 16, 0, 0);
}

// ---------------- CSR build ----------------
__global__ void count_deg_kernel(const int* __restrict__ dst, int* __restrict__ deg, int E) {
    int i = blockIdx.x * blockDim.x + threadIdx.x;
    if (i < E) atomicAdd(&deg[dst[i]], 1);
}

__global__ __launch_bounds__(256) void scan_partial_kernel(
    const int* __restrict__ deg, int* __restrict__ partials, int n) {
    const int t = threadIdx.x;
    const int i0 = blockIdx.x * 1024 + t * 4;
    int sum = 0;
#pragma unroll
    for (int j = 0; j < 4; j++) { int i = i0 + j; if (i < n) sum += deg[i]; }
#pragma unroll
    for (int off = 32; off; off >>= 1) sum += __shfl_down(sum, off);
    __shared__ int ws[4];
    int lane = t & 63, wid = t >> 6;
    if (lane == 0) ws[wid] = sum;
    __syncthreads();
    if (t == 0) partials[blockIdx.x] = ws[0] + ws[1] + ws[2] + ws[3];
}

__global__ void scan_partials_kernel(int* __restrict__ p, int nb) {
    const int lane = threadIdx.x;  // 64 threads
    int carry = 0;
    for (int base = 0; base < nb; base += 64) {
        int i = base + lane;
        int v = (i < nb) ? p[i] : 0;
        int orig = v;
#pragma unroll
        for (int off = 1; off < 64; off <<= 1) {
            int x = __shfl_up(v, off);
            if (lane >= off) v += x;
        }
        int ex = carry + v - orig;
        if (i < nb) p[i] = ex;
        carry += __shfl(v, 63);
    }
}

__global__ __launch_bounds__(256) void scan_final_kernel(
    const int* __restrict__ deg, const int* __restrict__ pscan,
    int* __restrict__ row_start, int n) {
    const int t = threadIdx.x;
    const int i0 = blockIdx.x * 1024 + t * 4;
    int v0 = (i0 + 0 < n) ? deg[i0 + 0] : 0;
    int v1 = (i0 + 1 < n) ? deg[i0 + 1] : 0;
    int v2 = (i0 + 2 < n) ? deg[i0 + 2] : 0;
    int v3 = (i0 + 3 < n) ? deg[i0 + 3] : 0;
    int tot = v0 + v1 + v2 + v3;
    int lane = t & 63, wid = t >> 6;
    int inc = tot;
#pragma unroll
    for (int off = 1; off < 64; off <<= 1) {
        int x = __shfl_up(inc, off);
        if (lane >= off) inc += x;
    }
    __shared__ int wsum[4];
    if (lane == 63) wsum[wid] = inc;
    __syncthreads();
    int wbase = 0;
    for (int w2 = 0; w2 < wid; w2++) wbase += wsum[w2];
    int r = wbase + inc - tot + pscan[blockIdx.x];
    r += v0; if (i0 + 0 < n) row_start[i0 + 1] = r;
    r += v1; if (i0 + 1 < n) row_start[i0 + 2] = r;
    r += v2; if (i0 + 2 < n) row_start[i0 + 3] = r;
    r += v3; if (i0 + 3 < n) row_start[i0 + 4] = r;
    if (blockIdx.x == 0 && t == 0) row_start[0] = 0;
}

__global__ void scatter_edges_kernel(const int* __restrict__ src, const int* __restrict__ dst,
                                     const int* __restrict__ row_start, int* __restrict__ cursor,
                                     int* __restrict__ csr, int E) {
    int i = blockIdx.x * blockDim.x + threadIdx.x;
    if (i < E) {
        int d = dst[i];
        int pos = atomicAdd(&cursor[d], 1);
        csr[row_start[d] + pos] = src[i];
    }
}

// ---------------- conversions ----------------
__global__ void f32_to_bf16_kernel(const float* __restrict__ in,
                                   unsigned short* __restrict__ out, int n4) {
    int i = blockIdx.x * blockDim.x + threadIdx.x;
    if (i >= n4) return;
    float4 v = *reinterpret_cast<const float4*>(in + (size_t)i * 4);
    ushort4 o = { f2b(v.x), f2b(v.y), f2b(v.z), f2b(v.w) };
    *reinterpret_cast<ushort4*>(out + (size_t)i * 4) = o;
}

// Wt[(n+noff)*Ktot + koff + k] = bf16(W[k*N + n])
__global__ void wt_transpose_kernel(const float* __restrict__ W, unsigned short* __restrict__ Wt,
                                    int K, int N, int koff, int Ktot, int noff) {
    int idx = blockIdx.x * blockDim.x + threadIdx.x;
    if (idx >= K * N) return;
    int k = idx / N, n = idx - k * N;
    Wt[(size_t)(n + noff) * Ktot + koff + k] = f2b(W[idx]);
}

// ---------------- aggregation ----------------
// One wave per node. Half-wave covers one edge's 512B row (32 lanes x 16B).
// 8 edges per half in flight (16/wave). Tail row-loads exec-masked (no traffic).
__global__ __launch_bounds__(256) void agg256_bf16(
    const unsigned short* __restrict__ hsrc, const int* __restrict__ row_start,
    const int* __restrict__ csr, unsigned short* __restrict__ out, int n) {
    int wv = (blockIdx.x * blockDim.x + threadIdx.x) >> 6;
    int lane = threadIdx.x & 63;
    if (wv >= n) return;
    int s0 = row_start[wv], s1 = row_start[wv + 1];
    int deg = s1 - s0;
    const int half = lane >> 5;
    const int li   = lane & 31;
    float a[8] = {0.f, 0.f, 0.f, 0.f, 0.f, 0.f, 0.f, 0.f};

    for (int base = s0; base < s1; base += 16) {
        int idx[8];
#pragma unroll
        for (int j = 0; j < 8; j++) {
            int e = base + half + 2 * j;
            idx[j] = csr[e < s1 ? e : s1 - 1];   // clamped 4B dup: harmless
        }
        uint4 v[8];
#pragma unroll
        for (int j = 0; j < 8; j++) {
            int e = base + half + 2 * j;
            v[j] = make_uint4(0u, 0u, 0u, 0u);
            if (e < s1)
                v[j] = *reinterpret_cast<const uint4*>(hsrc + (size_t)idx[j] * 256 + li * 8);
        }
#pragma unroll
        for (int j = 0; j < 8; j++) acc8(a, v[j]);
    }
#pragma unroll
    for (int k = 0; k < 8; k++) a[k] += __shfl_xor(a[k], 32);
    if (half == 0) {
        float sc = 1.0f / (float)max(deg, 1);
        uint4 o;
        o.x = ((unsigned)f2b(a[1] * sc) << 16) | f2b(a[0] * sc);
        o.y = ((unsigned)f2b(a[3] * sc) << 16) | f2b(a[2] * sc);
        o.z = ((unsigned)f2b(a[5] * sc) << 16) | f2b(a[4] * sc);
        o.w = ((unsigned)f2b(a[7] * sc) << 16) | f2b(a[6] * sc);
        *reinterpret_cast<uint4*>(out + (size_t)wv * 256 + li * 8) = o;
    }
}

// Final fused kernel: h2[v][:] = Sself[v][:] + mean_{s in N(v)} Tb[s][:] + b2
// One wave per node; 8 groups of 8 lanes; 16 edges in flight per wave.
__global__ __launch_bounds__(256) void agg64_final(
    const unsigned short* __restrict__ t, const int* __restrict__ row_start,
    const int* __restrict__ csr, const float* __restrict__ Sself,
    const float* __restrict__ b2, float* __restrict__ h2, int n) {
    int wv = (blockIdx.x * blockDim.x + threadIdx.x) >> 6;
    int lane = threadIdx.x & 63;
    if (wv >= n) return;
    int s0 = row_start[wv], s1 = row_start[wv + 1];
    int deg = s1 - s0;
    const int g  = lane >> 3;
    const int li = lane & 7;
    float a[8] = {0.f, 0.f, 0.f, 0.f, 0.f, 0.f, 0.f, 0.f};
    for (int base = s0 + g; base < s1; base += 16) {
        int e1 = base + 8;
        int i0 = csr[base];
        int i1 = csr[e1 < s1 ? e1 : s1 - 1];
        uint4 v0 = *reinterpret_cast<const uint4*>(t + (size_t)i0 * 64 + li * 8);
        uint4 v1 = make_uint4(0u, 0u, 0u, 0u);
        if (e1 < s1)
            v1 = *reinterpret_cast<const uint4*>(t + (size_t)i1 * 64 + li * 8);
        acc8(a, v0); acc8(a, v1);
    }
#pragma unroll
    for (int k = 0; k < 8; k++) {
        a[k] += __shfl_xor(a[k], 8);
        a[k] += __shfl_xor(a[k], 16);
        a[k] += __shfl_xor(a[k], 32);
    }
    if (g == 0) {
        float sc = 1.0f / (float)max(deg, 1);
        float4 s0v = *reinterpret_cast<const float4*>(Sself + (size_t)wv * 64 + li * 8);
        float4 s1v = *reinterpret_cast<const float4*>(Sself + (size_t)wv * 64 + li * 8 + 4);
        float4 bb0 = *reinterpret_cast<const float4*>(b2 + li * 8);
        float4 bb1 = *reinterpret_cast<const float4*>(b2 + li * 8 + 4);
        float4 o0 = make_float4(s0v.x + a[0] * sc + bb0.x, s0v.y + a[1] * sc + bb0.y,
                                s0v.z + a[2] * sc + bb0.z, s0v.w + a[3] * sc + bb0.w);
        float4 o1 = make_float4(s1v.x + a[4] * sc + bb1.x, s1v.y + a[5] * sc + bb1.y,
                                s1v.z + a[6] * sc + bb1.z, s1v.w + a[7] * sc + bb1.w);
        *reinterpret_cast<float4*>(h2 + (size_t)wv * 64 + li * 8) = o0;
        *reinterpret_cast<float4*>(h2 + (size_t)wv * 64 + li * 8 + 4) = o1;
    }
}

// ---------------- MFMA GEMM with async LDS staging ----------------
// C[M,Ntot] = act( [A|G] @ Wt^T + bias ); A/G bf16 [M][256], Wt bf16 [Ntot][Ktot].
// split mode: cols 0-63 -> fp32 outF [M][64]; cols 64-127 -> bf16 outB [M][64].
#define TM 128
#define TN 64
#define TK 32

__global__ __launch_bounds__(256) void gemm_mfma(
    const unsigned short* __restrict__ A, const unsigned short* __restrict__ G,
    const unsigned short* __restrict__ Wt, const float* __restrict__ bias,
    float* __restrict__ outF, unsigned short* __restrict__ outB,
    int M, int Ntot, int Ktot, int relu, int split) {
    __shared__ unsigned short Asb[TM][TK];   // unpadded: rows 64B, lane-linear for lds-dma
    __shared__ unsigned short Bsb[TN][TK];

    const int tid = threadIdx.x;
    const int row0 = blockIdx.x * TM;
    const int col0 = blockIdx.y * TN;

    const int w = tid >> 6, lane = tid & 63;
    const int mw = (w & 1) * 64;
    const int nw = (w >> 1) * 32;
    const int lm = lane & 15, lq = lane >> 4;
    const int lr = lane >> 2;         // 0..15 row-in-chunk
    const int lc = (lane & 3) * 8;    // 0/8/16/24 shorts (16B chunks)

    f32x4 acc[4][2];
#pragma unroll
    for (int i = 0; i < 4; i++)
#pragma unroll
        for (int j = 0; j < 2; j++) acc[i][j] = (f32x4)(0.f);

    for (int k0 = 0; k0 < Ktot; k0 += TK) {
        const unsigned short* __restrict__ Ap = (G != nullptr && k0 >= 256) ? G : A;
        const int kl = k0 & 255;
        // A tile: 128 rows x 64B; wave w stages rows [w*32, w*32+32) via 2 lds-dma
#pragma unroll
        for (int h = 0; h < 2; ++h) {
            int r16 = w * 32 + h * 16;
            int gr = row0 + r16 + lr;
            if (gr < M)
                gl_lds16(Ap + (size_t)gr * 256 + kl + lc, &Asb[r16][0]);
        }
        // B tile: 64 n-rows x 64B; wave w stages rows [w*16, w*16+16)
        {
            int n16 = w * 16;
            int gn = col0 + n16 + lr;
            gl_lds16(Wt + (size_t)gn * Ktot + k0 + lc, &Bsb[n16][0]);
        }
        __syncthreads();

        frag_ab a[4], b[2];
#pragma unroll
        for (int i = 0; i < 4; i++)
            a[i] = *reinterpret_cast<const frag_ab*>(&Asb[mw + i * 16 + lm][lq * 8]);
#pragma unroll
        for (int j = 0; j < 2; j++)
            b[j] = *reinterpret_cast<const frag_ab*>(&Bsb[nw + j * 16 + lm][lq * 8]);
#pragma unroll
        for (int i = 0; i < 4; i++)
#pragma unroll
            for (int j = 0; j < 2; j++)
                acc[i][j] = __builtin_amdgcn_mfma_f32_16x16x32_bf16(a[i], b[j], acc[i][j], 0, 0, 0);
        __syncthreads();
    }

#pragma unroll
    for (int i = 0; i < 4; i++) {
#pragma unroll
        for (int j = 0; j < 2; j++) {
            int cg = col0 + nw + j * 16 + lm;
#pragma unroll
            for (int r = 0; r < 4; r++) {
                int rg = row0 + mw + i * 16 + lq * 4 + r;
                if (rg >= M) continue;
                float v = acc[i][j][r];
                if (bias) v += bias[cg];
                if (relu) v = fmaxf(v, 0.f);
                if (split) {
                    if (cg < 64) outF[(size_t)rg * 64 + cg] = v;
                    else         outB[(size_t)rg * 64 + (cg - 64)] = f2b(v);
                } else {
                    if (outF) outF[(size_t)rg * Ntot + cg] = v;
                    if (outB) outB[(size_t)rg * Ntot + cg] = f2b(v);
                }
            }
        }
    }
}

// ---------------------------------------------------------------------------
extern "C" void kernel_launch(void* const* d_in, const int* in_sizes, int n_in,
                              void* d_out, int out_size, void* d_ws, size_t ws_size,
                              hipStream_t stream) {
    const float* x   = (const float*)d_in[0];
    const int*   src = (const int*)d_in[1];
    const int*   dst = (const int*)d_in[2];
    const float* Ws0 = (const float*)d_in[3];
    const float* Wn0 = (const float*)d_in[4];
    const float* b0  = (const float*)d_in[5];
    const float* Ws1 = (const float*)d_in[6];
    const float* Wn1 = (const float*)d_in[7];
    const float* b1  = (const float*)d_in[8];
    const float* Ws2 = (const float*)d_in[9];
    const float* Wn2 = (const float*)d_in[10];
    const float* b2  = (const float*)d_in[11];

    const int N = in_sizes[0] / 256;   // 50000
    const int E = in_sizes[1];         // 1600000

    float* out = (float*)d_out;
    float* h2 = out;                       // N x 64  (output 0)
    float* h1 = out + (size_t)N * 64;      // N x 256 (output 1, fp32)

    // ---- workspace layout ----
    char* w = (char*)d_ws;
    auto align16 = [](char* p) { return (char*)(((uintptr_t)p + 15) & ~(uintptr_t)15); };
    int* deg       = (int*)w;  w += (size_t)N * 4;
    int* cursor    = (int*)w;  w += (size_t)N * 4;
    int* row_start = (int*)w;  w += (size_t)(N + 1) * 4;
    int* partials  = (int*)w;  w += 256 * 4;
    int* csr       = (int*)w;  w += (size_t)E * 4;
    w = align16(w);
    unsigned short* Wt0   = (unsigned short*)w; w += (size_t)256 * 512 * 2;
    unsigned short* Wt1   = (unsigned short*)w; w += (size_t)256 * 512 * 2;
    unsigned short* Wt2   = (unsigned short*)w; w += (size_t)128 * 256 * 2;  // [Ws2t;Wn2t]
    w = align16(w);
    unsigned short* xb    = (unsigned short*)w; w += (size_t)N * 256 * 2;
    unsigned short* A1b   = (unsigned short*)w; w += (size_t)N * 256 * 2;
    unsigned short* H0b   = (unsigned short*)w; w += (size_t)N * 256 * 2;
    unsigned short* h1b   = (unsigned short*)w; w += (size_t)N * 256 * 2;
    // dead-region reuse for layer 2: xb dead after layer-0 gemm, A1b after layer-1 gemm
    unsigned short* Tb    = xb;                    // N x 64 bf16
    float*          Sself = (float*)A1b;           // N x 64 fp32

    const int nb = (N + 1023) / 1024;

    // ---- CSR build ----
    hipMemsetAsync(deg, 0, (size_t)N * 2 * 4, stream);
    count_deg_kernel<<<(E + 255) / 256, 256, 0, stream>>>(dst, deg, E);
    scan_partial_kernel<<<nb, 256, 0, stream>>>(deg, partials, N);
    scan_partials_kernel<<<1, 64, 0, stream>>>(partials, nb);
    scan_final_kernel<<<nb, 256, 0, stream>>>(deg, partials, row_start, N);
    scatter_edges_kernel<<<(E + 255) / 256, 256, 0, stream>>>(src, dst, row_start, cursor, csr, E);

    // ---- conversions ----
    {
        int n4 = N * 256 / 4;
        f32_to_bf16_kernel<<<(n4 + 255) / 256, 256, 0, stream>>>(x, xb, n4);
    }
    {
        int nt = 256 * 256;
        wt_transpose_kernel<<<(nt + 255) / 256, 256, 0, stream>>>(Ws0, Wt0, 256, 256, 0,   512, 0);
        wt_transpose_kernel<<<(nt + 255) / 256, 256, 0, stream>>>(Wn0, Wt0, 256, 256, 256, 512, 0);
        wt_transpose_kernel<<<(nt + 255) / 256, 256, 0, stream>>>(Ws1, Wt1, 256, 256, 0,   512, 0);
        wt_transpose_kernel<<<(nt + 255) / 256, 256, 0, stream>>>(Wn1, Wt1, 256, 256, 256, 512, 0);
        int nt2 = 256 * 64;
        wt_transpose_kernel<<<(nt2 + 255) / 256, 256, 0, stream>>>(Ws2, Wt2, 256, 64, 0, 256, 0);
        wt_transpose_kernel<<<(nt2 + 255) / 256, 256, 0, stream>>>(Wn2, Wt2, 256, 64, 0, 256, 64);
    }

    dim3 aggGrid((N + 3) / 4);
    dim3 gBig((N + TM - 1) / TM, 256 / TN);    // 391 x 4
    dim3 gSplit((N + TM - 1) / TM, 2);         // 391 x 2 (stacked 128-col)

    // ---- layer 0 ----
    agg256_bf16<<<aggGrid, 256, 0, stream>>>(xb, row_start, csr, A1b, N);
    gemm_mfma<<<gBig, 256, 0, stream>>>(xb, A1b, Wt0, b0, nullptr, H0b,
                                        N, 256, 512, 1, 0);
    // ---- layer 1 ----
    agg256_bf16<<<aggGrid, 256, 0, stream>>>(H0b, row_start, csr, A1b, N);
    gemm_mfma<<<gBig, 256, 0, stream>>>(H0b, A1b, Wt1, b1, h1, h1b,
                                        N, 256, 512, 1, 0);
    // ---- layer 2: one stacked gemm + fused aggregate/add ----
    gemm_mfma<<<gSplit, 256, 0, stream>>>(h1b, nullptr, Wt2, nullptr, Sself, Tb,
                                          N, 128, 256, 0, 1);
    agg64_final<<<aggGrid, 256, 0, stream>>>(Tb, row_start, csr, Sself, b2, h2, N);
}

// Round 5
// 635.078 us; speedup vs baseline: 2.2124x; 1.1864x over previous
//
#include <hip/hip_runtime.h>
#include <hip/hip_bf16.h>
#include <cstdint>

// ---------------------------------------------------------------------------
// GraphSAGE inference. bf16 GEMM plane (MFMA, async LDS staging); fp8 e4m3
// aggregation tables (gather traffic halved; fp32 accumulate).
//   CSR build -> agg256_fp8(x8) -> A1b
//   gemm([xb|A1b]@Wt0)+b0 relu -> H0b(bf16) + H08(fp8)
//   agg256_fp8(H08) -> A1b
//   gemm([H0b|A1b]@Wt1)+b1 relu -> h1(fp32) + h1b(bf16)
//   gemm(h1b@[Ws2t;Wn2t]) -> Sself(fp32), Tb(bf16)
//   agg64_final: h2 = Sself + mean_csr(Tb) + b2
// ---------------------------------------------------------------------------

typedef __attribute__((ext_vector_type(8))) short  frag_ab;  // 8 bf16
typedef __attribute__((ext_vector_type(4))) float  f32x4;
typedef __attribute__((ext_vector_type(2))) float  vf2;

__device__ __forceinline__ unsigned short f2b(float f) {
    __hip_bfloat16 h = __float2bfloat16(f);
    return *reinterpret_cast<unsigned short*>(&h);
}
__device__ __forceinline__ unsigned char f2p8(float f) {
    int p = __builtin_amdgcn_cvt_pk_fp8_f32(f, f, 0, false);
    return (unsigned char)(p & 0xff);
}
// accumulate 8 bf16 (as uint4) into 8 fp32
__device__ __forceinline__ void acc8(float* a, uint4 v) {
    a[0] += __uint_as_float(v.x << 16);
    a[1] += __uint_as_float(v.x & 0xffff0000u);
    a[2] += __uint_as_float(v.y << 16);
    a[3] += __uint_as_float(v.y & 0xffff0000u);
    a[4] += __uint_as_float(v.z << 16);
    a[5] += __uint_as_float(v.z & 0xffff0000u);
    a[6] += __uint_as_float(v.w << 16);
    a[7] += __uint_as_float(v.w & 0xffff0000u);
}
// accumulate 8 fp8 (as uint2) into 8 fp32 via HW cvt
__device__ __forceinline__ void acc8p(float* a, uint2 v) {
    vf2 f0 = __builtin_amdgcn_cvt_pk_f32_fp8(v.x, false);
    vf2 f1 = __builtin_amdgcn_cvt_pk_f32_fp8(v.x, true);
    vf2 f2 = __builtin_amdgcn_cvt_pk_f32_fp8(v.y, false);
    vf2 f3 = __builtin_amdgcn_cvt_pk_f32_fp8(v.y, true);
    a[0] += f0.x; a[1] += f0.y; a[2] += f1.x; a[3] += f1.y;
    a[4] += f2.x; a[5] += f2.y; a[6] += f3.x; a[7] += f3.y;
}

// async global->LDS, 16B per lane; lds base wave-uniform (HW adds lane*16)
__device__ __forceinline__ void gl_lds16(const void* g, void* l) {
    __builtin_amdgcn_global_load_lds(
        (const __attribute__((address_space(1))) unsigned int*)g,
        (__attribute__((address_space(3))) unsigned int*)l, 16, 0, 0);
}

// ---------------- CSR build ----------------
__global__ void count_deg_kernel(const int* __restrict__ dst, int* __restrict__ deg, int E) {
    int i = blockIdx.x * blockDim.x + threadIdx.x;
    if (i < E) atomicAdd(&deg[dst[i]], 1);
}

__global__ __launch_bounds__(256) void scan_partial_kernel(
    const int* __restrict__ deg, int* __restrict__ partials, int n) {
    const int t = threadIdx.x;
    const int i0 = blockIdx.x * 1024 + t * 4;
    int sum = 0;
#pragma unroll
    for (int j = 0; j < 4; j++) { int i = i0 + j; if (i < n) sum += deg[i]; }
#pragma unroll
    for (int off = 32; off; off >>= 1) sum += __shfl_down(sum, off);
    __shared__ int ws[4];
    int lane = t & 63, wid = t >> 6;
    if (lane == 0) ws[wid] = sum;
    __syncthreads();
    if (t == 0) partials[blockIdx.x] = ws[0] + ws[1] + ws[2] + ws[3];
}

__global__ void scan_partials_kernel(int* __restrict__ p, int nb) {
    const int lane = threadIdx.x;  // 64 threads
    int carry = 0;
    for (int base = 0; base < nb; base += 64) {
        int i = base + lane;
        int v = (i < nb) ? p[i] : 0;
        int orig = v;
#pragma unroll
        for (int off = 1; off < 64; off <<= 1) {
            int x = __shfl_up(v, off);
            if (lane >= off) v += x;
        }
        int ex = carry + v - orig;
        if (i < nb) p[i] = ex;
        carry += __shfl(v, 63);
    }
}

__global__ __launch_bounds__(256) void scan_final_kernel(
    const int* __restrict__ deg, const int* __restrict__ pscan,
    int* __restrict__ row_start, int n) {
    const int t = threadIdx.x;
    const int i0 = blockIdx.x * 1024 + t * 4;
    int v0 = (i0 + 0 < n) ? deg[i0 + 0] : 0;
    int v1 = (i0 + 1 < n) ? deg[i0 + 1] : 0;
    int v2 = (i0 + 2 < n) ? deg[i0 + 2] : 0;
    int v3 = (i0 + 3 < n) ? deg[i0 + 3] : 0;
    int tot = v0 + v1 + v2 + v3;
    int lane = t & 63, wid = t >> 6;
    int inc = tot;
#pragma unroll
    for (int off = 1; off < 64; off <<= 1) {
        int x = __shfl_up(inc, off);
        if (lane >= off) inc += x;
    }
    __shared__ int wsum[4];
    if (lane == 63) wsum[wid] = inc;
    __syncthreads();
    int wbase = 0;
    for (int w2 = 0; w2 < wid; w2++) wbase += wsum[w2];
    int r = wbase + inc - tot + pscan[blockIdx.x];
    r += v0; if (i0 + 0 < n) row_start[i0 + 1] = r;
    r += v1; if (i0 + 1 < n) row_start[i0 + 2] = r;
    r += v2; if (i0 + 2 < n) row_start[i0 + 3] = r;
    r += v3; if (i0 + 3 < n) row_start[i0 + 4] = r;
    if (blockIdx.x == 0 && t == 0) row_start[0] = 0;
}

__global__ void scatter_edges_kernel(const int* __restrict__ src, const int* __restrict__ dst,
                                     const int* __restrict__ row_start, int* __restrict__ cursor,
                                     int* __restrict__ csr, int E) {
    int i = blockIdx.x * blockDim.x + threadIdx.x;
    if (i < E) {
        int d = dst[i];
        int pos = atomicAdd(&cursor[d], 1);
        csr[row_start[d] + pos] = src[i];
    }
}

// ---------------- conversions ----------------
// x -> bf16 (xb) + fp8 (x8), 4 elems/thread
__global__ void conv_x_kernel(const float* __restrict__ in, unsigned short* __restrict__ outb,
                              unsigned char* __restrict__ outp, int n4) {
    int i = blockIdx.x * blockDim.x + threadIdx.x;
    if (i >= n4) return;
    float4 v = *reinterpret_cast<const float4*>(in + (size_t)i * 4);
    ushort4 ob = { f2b(v.x), f2b(v.y), f2b(v.z), f2b(v.w) };
    *reinterpret_cast<ushort4*>(outb + (size_t)i * 4) = ob;
    int p0 = __builtin_amdgcn_cvt_pk_fp8_f32(v.x, v.y, 0, false);
    int p1 = __builtin_amdgcn_cvt_pk_fp8_f32(v.z, v.w, 0, false);
    unsigned int packed = (unsigned int)(p0 & 0xffff) | ((unsigned int)p1 << 16);
    *reinterpret_cast<unsigned int*>(outp + (size_t)i * 4) = packed;
}

// all six weight transposes in one dispatch.
// blocks [0,256) Ws0 | [256,512) Wn0 | [512,768) Ws1 | [768,1024) Wn1
// [1024,1088) Ws2 | [1088,1152) Wn2
__global__ __launch_bounds__(256) void wt_all_kernel(
    const float* __restrict__ Ws0, const float* __restrict__ Wn0,
    const float* __restrict__ Ws1, const float* __restrict__ Wn1,
    const float* __restrict__ Ws2, const float* __restrict__ Wn2,
    unsigned short* __restrict__ Wt0, unsigned short* __restrict__ Wt1,
    unsigned short* __restrict__ Wt2) {
    int b = blockIdx.x;
    const float* W; unsigned short* Wt; int N, koff, Ktot, noff, idx;
    if (b < 1024) {
        int seg = b >> 8; idx = (b & 255) * 256 + threadIdx.x;
        N = 256; Ktot = 512; noff = 0;
        if (seg == 0)      { W = Ws0; Wt = Wt0; koff = 0;   }
        else if (seg == 1) { W = Wn0; Wt = Wt0; koff = 256; }
        else if (seg == 2) { W = Ws1; Wt = Wt1; koff = 0;   }
        else               { W = Wn1; Wt = Wt1; koff = 256; }
    } else {
        int seg = (b - 1024) >> 6; idx = ((b - 1024) & 63) * 256 + threadIdx.x;
        N = 64; Ktot = 256; koff = 0;
        if (seg == 0) { W = Ws2; Wt = Wt2; noff = 0;  }
        else          { W = Wn2; Wt = Wt2; noff = 64; }
    }
    int k = idx / N, n = idx - k * N;
    Wt[(size_t)(n + noff) * Ktot + koff + k] = f2b(W[(size_t)idx]);
}

// ---------------- aggregation ----------------
// fp8 rows (256B). Half-wave covers one edge's row (32 lanes x 8B).
// 8 edges per half in flight (16/wave). bf16 output row.
__global__ __launch_bounds__(256) void agg256_fp8(
    const unsigned char* __restrict__ hsrc, const int* __restrict__ row_start,
    const int* __restrict__ csr, unsigned short* __restrict__ out, int n) {
    int wv = (blockIdx.x * blockDim.x + threadIdx.x) >> 6;
    int lane = threadIdx.x & 63;
    if (wv >= n) return;
    int s0 = row_start[wv], s1 = row_start[wv + 1];
    int deg = s1 - s0;
    const int half = lane >> 5;
    const int li   = lane & 31;   // byte offset li*8: fp8 cols li*8..li*8+7
    float a[8] = {0.f, 0.f, 0.f, 0.f, 0.f, 0.f, 0.f, 0.f};

    for (int base = s0; base < s1; base += 16) {
        int idx[8];
#pragma unroll
        for (int j = 0; j < 8; j++) {
            int e = base + half + 2 * j;
            idx[j] = csr[e < s1 ? e : s1 - 1];
        }
        uint2 v[8];
#pragma unroll
        for (int j = 0; j < 8; j++) {
            int e = base + half + 2 * j;
            v[j] = make_uint2(0u, 0u);
            if (e < s1)
                v[j] = *reinterpret_cast<const uint2*>(hsrc + (size_t)idx[j] * 256 + li * 8);
        }
#pragma unroll
        for (int j = 0; j < 8; j++) acc8p(a, v[j]);
    }
#pragma unroll
    for (int k = 0; k < 8; k++) a[k] += __shfl_xor(a[k], 32);
    if (half == 0) {
        float sc = 1.0f / (float)max(deg, 1);
        uint4 o;
        o.x = ((unsigned)f2b(a[1] * sc) << 16) | f2b(a[0] * sc);
        o.y = ((unsigned)f2b(a[3] * sc) << 16) | f2b(a[2] * sc);
        o.z = ((unsigned)f2b(a[5] * sc) << 16) | f2b(a[4] * sc);
        o.w = ((unsigned)f2b(a[7] * sc) << 16) | f2b(a[6] * sc);
        *reinterpret_cast<uint4*>(out + (size_t)wv * 256 + li * 8) = o;
    }
}

// h2[v][:] = Sself[v][:] + mean_{s in N(v)} Tb[s][:] + b2 ; Tb bf16 64-wide
__global__ __launch_bounds__(256) void agg64_final(
    const unsigned short* __restrict__ t, const int* __restrict__ row_start,
    const int* __restrict__ csr, const float* __restrict__ Sself,
    const float* __restrict__ b2, float* __restrict__ h2, int n) {
    int wv = (blockIdx.x * blockDim.x + threadIdx.x) >> 6;
    int lane = threadIdx.x & 63;
    if (wv >= n) return;
    int s0 = row_start[wv], s1 = row_start[wv + 1];
    int deg = s1 - s0;
    const int g  = lane >> 3;
    const int li = lane & 7;
    float a[8] = {0.f, 0.f, 0.f, 0.f, 0.f, 0.f, 0.f, 0.f};
    for (int base = s0 + g; base < s1; base += 16) {
        int e1 = base + 8;
        int i0 = csr[base];
        int i1 = csr[e1 < s1 ? e1 : s1 - 1];
        uint4 v0 = *reinterpret_cast<const uint4*>(t + (size_t)i0 * 64 + li * 8);
        uint4 v1 = make_uint4(0u, 0u, 0u, 0u);
        if (e1 < s1)
            v1 = *reinterpret_cast<const uint4*>(t + (size_t)i1 * 64 + li * 8);
        acc8(a, v0); acc8(a, v1);
    }
#pragma unroll
    for (int k = 0; k < 8; k++) {
        a[k] += __shfl_xor(a[k], 8);
        a[k] += __shfl_xor(a[k], 16);
        a[k] += __shfl_xor(a[k], 32);
    }
    if (g == 0) {
        float sc = 1.0f / (float)max(deg, 1);
        float4 s0v = *reinterpret_cast<const float4*>(Sself + (size_t)wv * 64 + li * 8);
        float4 s1v = *reinterpret_cast<const float4*>(Sself + (size_t)wv * 64 + li * 8 + 4);
        float4 bb0 = *reinterpret_cast<const float4*>(b2 + li * 8);
        float4 bb1 = *reinterpret_cast<const float4*>(b2 + li * 8 + 4);
        float4 o0 = make_float4(s0v.x + a[0] * sc + bb0.x, s0v.y + a[1] * sc + bb0.y,
                                s0v.z + a[2] * sc + bb0.z, s0v.w + a[3] * sc + bb0.w);
        float4 o1 = make_float4(s1v.x + a[4] * sc + bb1.x, s1v.y + a[5] * sc + bb1.y,
                                s1v.z + a[6] * sc + bb1.z, s1v.w + a[7] * sc + bb1.w);
        *reinterpret_cast<float4*>(h2 + (size_t)wv * 64 + li * 8) = o0;
        *reinterpret_cast<float4*>(h2 + (size_t)wv * 64 + li * 8 + 4) = o1;
    }
}

// ---------------- MFMA GEMM with async LDS staging ----------------
// C[M,Ntot] = act( [A|G] @ Wt^T + bias ); A/G bf16 [M][256], Wt bf16 [Ntot][Ktot].
// Non-split: outF fp32 [M][Ntot] (opt), outB bf16 (opt), outP fp8 (opt).
// split: cols 0-63 -> fp32 outF [M][64]; cols 64-127 -> bf16 outB [M][64].
#define TM 128
#define TN 64
#define TK 32

__global__ __launch_bounds__(256) void gemm_mfma(
    const unsigned short* __restrict__ A, const unsigned short* __restrict__ G,
    const unsigned short* __restrict__ Wt, const float* __restrict__ bias,
    float* __restrict__ outF, unsigned short* __restrict__ outB,
    unsigned char* __restrict__ outP,
    int M, int Ntot, int Ktot, int relu, int split) {
    __shared__ unsigned short Asb[TM][TK];   // unpadded: lane-linear for lds-dma
    __shared__ unsigned short Bsb[TN][TK];

    const int tid = threadIdx.x;
    const int row0 = blockIdx.x * TM;
    const int col0 = blockIdx.y * TN;

    const int w = tid >> 6, lane = tid & 63;
    const int mw = (w & 1) * 64;
    const int nw = (w >> 1) * 32;
    const int lm = lane & 15, lq = lane >> 4;
    const int lr = lane >> 2;
    const int lc = (lane & 3) * 8;

    f32x4 acc[4][2];
#pragma unroll
    for (int i = 0; i < 4; i++)
#pragma unroll
        for (int j = 0; j < 2; j++) acc[i][j] = (f32x4)(0.f);

    for (int k0 = 0; k0 < Ktot; k0 += TK) {
        const unsigned short* __restrict__ Ap = (G != nullptr && k0 >= 256) ? G : A;
        const int kl = k0 & 255;
#pragma unroll
        for (int h = 0; h < 2; ++h) {
            int r16 = w * 32 + h * 16;
            int gr = row0 + r16 + lr;
            if (gr < M)
                gl_lds16(Ap + (size_t)gr * 256 + kl + lc, &Asb[r16][0]);
        }
        {
            int n16 = w * 16;
            int gn = col0 + n16 + lr;
            gl_lds16(Wt + (size_t)gn * Ktot + k0 + lc, &Bsb[n16][0]);
        }
        __syncthreads();

        frag_ab a[4], b[2];
#pragma unroll
        for (int i = 0; i < 4; i++)
            a[i] = *reinterpret_cast<const frag_ab*>(&Asb[mw + i * 16 + lm][lq * 8]);
#pragma unroll
        for (int j = 0; j < 2; j++)
            b[j] = *reinterpret_cast<const frag_ab*>(&Bsb[nw + j * 16 + lm][lq * 8]);
#pragma unroll
        for (int i = 0; i < 4; i++)
#pragma unroll
            for (int j = 0; j < 2; j++)
                acc[i][j] = __builtin_amdgcn_mfma_f32_16x16x32_bf16(a[i], b[j], acc[i][j], 0, 0, 0);
        __syncthreads();
    }

#pragma unroll
    for (int i = 0; i < 4; i++) {
#pragma unroll
        for (int j = 0; j < 2; j++) {
            int cg = col0 + nw + j * 16 + lm;
#pragma unroll
            for (int r = 0; r < 4; r++) {
                int rg = row0 + mw + i * 16 + lq * 4 + r;
                if (rg >= M) continue;
                float v = acc[i][j][r];
                if (bias) v += bias[cg];
                if (relu) v = fmaxf(v, 0.f);
                if (split) {
                    if (cg < 64) outF[(size_t)rg * 64 + cg] = v;
                    else         outB[(size_t)rg * 64 + (cg - 64)] = f2b(v);
                } else {
                    if (outF) outF[(size_t)rg * Ntot + cg] = v;
                    if (outB) outB[(size_t)rg * Ntot + cg] = f2b(v);
                    if (outP) outP[(size_t)rg * Ntot + cg] = f2p8(v);
                }
            }
        }
    }
}

// ---------------------------------------------------------------------------
extern "C" void kernel_launch(void* const* d_in, const int* in_sizes, int n_in,
                              void* d_out, int out_size, void* d_ws, size_t ws_size,
                              hipStream_t stream) {
    const float* x   = (const float*)d_in[0];
    const int*   src = (const int*)d_in[1];
    const int*   dst = (const int*)d_in[2];
    const float* Ws0 = (const float*)d_in[3];
    const float* Wn0 = (const float*)d_in[4];
    const float* b0  = (const float*)d_in[5];
    const float* Ws1 = (const float*)d_in[6];
    const float* Wn1 = (const float*)d_in[7];
    const float* b1  = (const float*)d_in[8];
    const float* Ws2 = (const float*)d_in[9];
    const float* Wn2 = (const float*)d_in[10];
    const float* b2  = (const float*)d_in[11];

    const int N = in_sizes[0] / 256;   // 50000
    const int E = in_sizes[1];         // 1600000

    float* out = (float*)d_out;
    float* h2 = out;                       // N x 64  (output 0)
    float* h1 = out + (size_t)N * 64;      // N x 256 (output 1, fp32)

    // ---- workspace layout ----
    char* w = (char*)d_ws;
    auto align16 = [](char* p) { return (char*)(((uintptr_t)p + 15) & ~(uintptr_t)15); };
    int* deg       = (int*)w;  w += (size_t)N * 4;
    int* cursor    = (int*)w;  w += (size_t)N * 4;
    int* row_start = (int*)w;  w += (size_t)(N + 1) * 4;
    int* partials  = (int*)w;  w += 256 * 4;
    int* csr       = (int*)w;  w += (size_t)E * 4;
    w = align16(w);
    unsigned short* Wt0   = (unsigned short*)w; w += (size_t)256 * 512 * 2;
    unsigned short* Wt1   = (unsigned short*)w; w += (size_t)256 * 512 * 2;
    unsigned short* Wt2   = (unsigned short*)w; w += (size_t)128 * 256 * 2;  // [Ws2t;Wn2t]
    w = align16(w);
    unsigned short* xb    = (unsigned short*)w; w += (size_t)N * 256 * 2;
    unsigned short* A1b   = (unsigned short*)w; w += (size_t)N * 256 * 2;
    unsigned short* H0b   = (unsigned short*)w; w += (size_t)N * 256 * 2;
    unsigned short* h1b   = (unsigned short*)w; w += (size_t)N * 256 * 2;
    // dead-region aliases (zero extra workspace):
    unsigned char* x8  = (unsigned char*)H0b;  // dead once gemm0 writes H0b
    unsigned char* H08 = (unsigned char*)h1b;  // consumed by agg#2 before gemm1 writes h1b
    unsigned short* Tb    = xb;                // xb dead after gemm0
    float*          Sself = (float*)A1b;       // A1b dead after gemm1

    const int nb = (N + 1023) / 1024;

    // ---- CSR build ----
    hipMemsetAsync(deg, 0, (size_t)N * 2 * 4, stream);
    count_deg_kernel<<<(E + 255) / 256, 256, 0, stream>>>(dst, deg, E);
    scan_partial_kernel<<<nb, 256, 0, stream>>>(deg, partials, N);
    scan_partials_kernel<<<1, 64, 0, stream>>>(partials, nb);
    scan_final_kernel<<<nb, 256, 0, stream>>>(deg, partials, row_start, N);
    scatter_edges_kernel<<<(E + 255) / 256, 256, 0, stream>>>(src, dst, row_start, cursor, csr, E);

    // ---- conversions ----
    {
        int n4 = N * 256 / 4;
        conv_x_kernel<<<(n4 + 255) / 256, 256, 0, stream>>>(x, xb, x8, n4);
    }
    wt_all_kernel<<<1152, 256, 0, stream>>>(Ws0, Wn0, Ws1, Wn1, Ws2, Wn2, Wt0, Wt1, Wt2);

    dim3 aggGrid((N + 3) / 4);
    dim3 gBig((N + TM - 1) / TM, 256 / TN);    // 391 x 4
    dim3 gSplit((N + TM - 1) / TM, 2);         // 391 x 2

    // ---- layer 0 ----
    agg256_fp8<<<aggGrid, 256, 0, stream>>>(x8, row_start, csr, A1b, N);
    gemm_mfma<<<gBig, 256, 0, stream>>>(xb, A1b, Wt0, b0, nullptr, H0b, H08,
                                        N, 256, 512, 1, 0);
    // ---- layer 1 ----
    agg256_fp8<<<aggGrid, 256, 0, stream>>>(H08, row_start, csr, A1b, N);
    gemm_mfma<<<gBig, 256, 0, stream>>>(H0b, A1b, Wt1, b1, h1, h1b, nullptr,
                                        N, 256, 512, 1, 0);
    // ---- layer 2: stacked gemm + fused aggregate/add ----
    gemm_mfma<<<gSplit, 256, 0, stream>>>(h1b, nullptr, Wt2, nullptr, Sself, Tb, nullptr,
                                          N, 128, 256, 0, 1);
    agg64_final<<<aggGrid, 256, 0, stream>>>(Tb, row_start, csr, Sself, b2, h2, N);
}